// Round 7
// baseline (19478.960 us; speedup 1.0000x reference)
//
#include <hip/hip_runtime.h>
#include <hip/hip_bf16.h>
#include <stdint.h>

// Problem dims
#define Bn 128
#define Tn 512
#define En 512
#define Hn 2048
#define Vn 32000
#define R0 8           // h0 ring depth
#define R1 4           // h1 ring depth
#define HSLOT (Bn*Hn)  // elements per h slot

#define NREP 8
#define FXS 8192       // fX singles base: + g*16
#define FLAG_WORDS 16384

typedef float f32x4 __attribute__((ext_vector_type(4)));
typedef short bf16x8 __attribute__((ext_vector_type(8)));
typedef unsigned long long u64;

__device__ __forceinline__ unsigned short f2b(float f) {
  uint32_t x = __builtin_bit_cast(uint32_t, f);
  uint32_t r = x + 0x7FFFu + ((x >> 16) & 1u);
  return (unsigned short)(r >> 16);
}

// ---- MALL-coherent ops (r2-r4 proven): relaxed agent-scope atomics ----
union F32x4u { f32x4 v; u64 q[2]; };
__device__ __forceinline__ f32x4 ld_p(const float* p) {
  F32x4u u;
  u.q[0] = __hip_atomic_load((const u64*)p,     __ATOMIC_RELAXED, __HIP_MEMORY_SCOPE_AGENT);
  u.q[1] = __hip_atomic_load((const u64*)p + 1, __ATOMIC_RELAXED, __HIP_MEMORY_SCOPE_AGENT);
  return u.v;
}
__device__ __forceinline__ void st_p(float* p, f32x4 x) {
  F32x4u u; u.v = x;
  __hip_atomic_store((u64*)p,     u.q[0], __ATOMIC_RELAXED, __HIP_MEMORY_SCOPE_AGENT);
  __hip_atomic_store((u64*)p + 1, u.q[1], __ATOMIC_RELAXED, __HIP_MEMORY_SCOPE_AGENT);
}
__device__ __forceinline__ uint32_t ldf(const uint32_t* p) {
  return __hip_atomic_load(p, __ATOMIC_RELAXED, __HIP_MEMORY_SCOPE_AGENT);
}
__device__ __forceinline__ void stf(uint32_t* p, uint32_t v) {
  __hip_atomic_store(p, v, __ATOMIC_RELAXED, __HIP_MEMORY_SCOPE_AGENT);
}
__device__ __forceinline__ void drain_then_sync() {
  asm volatile("s_waitcnt vmcnt(0)" ::: "memory");
  __syncthreads();
}

// ---------------- init / pack kernels ----------------

__global__ void zero3(uint32_t* a, int na, uint32_t* b, int nb, uint32_t* c, int nc) {
  int i = blockIdx.x * 256 + threadIdx.x;
  if (i < na) a[i] = 0u;
  if (i < nb) b[i] = 0u;
  if (i < nc) c[i] = 0u;
}

__global__ void pack_bias(const float* bih0, const float* bhh0,
                          const float* bih1, const float* bhh1,
                          float* bias0, float* bias1) {
  int i = blockIdx.x * 256 + threadIdx.x;
  bias0[i] = bih0[i] + bhh0[i];
  bias1[i] = bih1[i] + bhh1[i];
}

// Generic 32-col-group weight packer. src: [2048 x Kd] row-major.
// Per group g (64 groups): packets (kt*2+ct)*64+l ; lane l elem j:
//   src[col = g*32 + ct*16 + (l&15)][k = kt*32 + (l>>4)*8 + j]
__global__ void pack_w32(const float* __restrict__ src, int Kd, uint4* __restrict__ img) {
  int tid = blockIdx.x * 256 + threadIdx.x;   // 64 * Kd * 4 total
  int per = Kd * 4;
  int g = tid / per, p = tid - g * per;
  int l = p & 63, q = p >> 6;
  int ct = q & 1, kt = q >> 1;
  int col = g * 32 + ct * 16 + (l & 15);
  int k0 = kt * 32 + (l >> 4) * 8;
  const float* s = src + (size_t)col * Kd + k0;
  unsigned short o[8];
#pragma unroll
  for (int j = 0; j < 8; ++j) o[j] = f2b(s[j]);
  img[tid] = *reinterpret_cast<uint4*>(o);
}

// W1 images: 32 groups of 16 cols, K=2048 (unchanged from r4)
__global__ void pack_imgW1(const float* __restrict__ W1, uint4* __restrict__ img) {
  int tid = blockIdx.x * 256 + threadIdx.x;
  int grp = tid >> 12;
  int p = tid & 4095;
  int l = p & 63;
  int kt = p >> 6;
  int col = grp * 16 + (l & 15);
  int k0 = kt * 32 + (l >> 4) * 8;
  const float* src = W1 + (size_t)col * Hn + k0;
  unsigned short o[8];
#pragma unroll
  for (int j = 0; j < 8; ++j) o[j] = f2b(src[j]);
  img[tid] = *reinterpret_cast<uint4*>(o);
}

// W2 images: 500 groups of 64 cols, K=512 (unchanged from r4)
__global__ void pack_imgW2(const float* __restrict__ W2, uint4* __restrict__ img) {
  int tid = blockIdx.x * 256 + threadIdx.x;
  int grp = tid >> 12;
  int p = tid & 4095;
  int l = p & 63;
  int ckt = p >> 6;
  int ct = ckt & 3, kt = ckt >> 2;
  int col = grp * 64 + ct * 16 + (l & 15);
  int k0 = kt * 32 + (l >> 4) * 8;
  const float* src = W2 + (size_t)col * En + k0;
  unsigned short o[8];
#pragma unroll
  for (int j = 0; j < 8; ++j) o[j] = f2b(src[j]);
  img[tid] = *reinterpret_cast<uint4*>(o);
}

__global__ void gather_x(const int* __restrict__ ids, const float* __restrict__ emb,
                         uint4* __restrict__ xall) {
  int tid = blockIdx.x * 256 + threadIdx.x;
  int t = tid >> 13;
  int r = tid & 8191;
  int b = r >> 6;
  int e8 = r & 63;
  int id = ids[b * Tn + t];
  const float* src = emb + (size_t)id * En + e8 * 8;
  unsigned short o[8];
#pragma unroll
  for (int j = 0; j < 8; ++j) o[j] = f2b(src[j]);
  xall[tid] = *reinterpret_cast<uint4*>(o);
}

// ---------------- persistent RNN kernel v7: hop-free critical path ----------------
// 256 blocks x 512 threads. role = blk>>6, g = blk&63 (64 groups of 32 cols):
//  role0 h0-P0: acc = Whh0[g-cols] . h0[t-1] (K=2048), + xpbuf + bias0 -> tanh -> h0[t], fA0[g]
//  role1 P1x  : xpbuf[t&1] = Wih0[g-cols] . x_t (K=512); runs ahead (ring 2), fX[g]
//  role2 h1-P0: acc = Wih1[g-cols] . h0[t] (K=2048), + bpbuf + bias1 -> tanh -> h1[t], fB0[g]
//  role3 h1-P1: bpbuf[t&1] = Whh1[g-cols] . h1[t-1] (K=2048), fP1[g]
// All cross-block data/flags via MALL (agent atomics / sc0 sc1 system loads) — r4-proven domain.
// Waits (audited for termination, no cycles):
//  role0@t: fA0[all]>=t ; fX[g]>=t+1 ; (t+1>R0): fB0[all]>=t+1-R0
//  role1@t: (t>=2): fA0[g]>=t-1            (xpbuf ring-2 overwrite safety)
//  role2@t: fA0[all]>=t+1 ; fP1[g]>=t+1 ; (t+2>R1): fP1[all]>=t+2-R1 (h1ring clobber)
//  role3@t: fB0[all]>=t                    (also covers bpbuf ring-2: fB0[g]>=t => P0 consumed t-1)
__global__ __launch_bounds__(512, 1) void rnn_persist(
    const uint4* __restrict__ imgWhh0, const uint4* __restrict__ imgWih0,
    const uint4* __restrict__ imgWih1, const uint4* __restrict__ imgWhh1,
    const unsigned short* __restrict__ xall,
    unsigned short* __restrict__ h0ring, unsigned short* __restrict__ h1ring,
    float* __restrict__ xpbuf, float* __restrict__ bpbuf,
    const float* __restrict__ bias0, const float* __restrict__ bias1,
    uint32_t* flags) {
  __shared__ uint4 smem[8192];   // 128 KiB weights
  __shared__ f32x4 rbuf[1024];   // 16 KiB acc-reduce buffer
  const int tid = threadIdx.x;
  const int w = tid >> 6, l = tid & 63, l15 = l & 15, kq = l >> 4;
  const int wh = w & 3, half = w >> 2;
  const int blk = blockIdx.x;
  const int role = blk >> 6, g = blk & 63;
  const int myrep = blk & (NREP - 1);
  const uint32_t* fA0r = flags + (size_t)myrep * 1024;
  const uint32_t* fB0r = flags + (size_t)myrep * 1024 + 128;
  const uint32_t* fP1r = flags + (size_t)myrep * 1024 + 256;

  // stage weights
  const uint4* wsrc; int npkt, Kd;
  if (role == 0)      { wsrc = imgWhh0 + (size_t)g * 8192; npkt = 8192; Kd = 2048; }
  else if (role == 1) { wsrc = imgWih0 + (size_t)g * 2048; npkt = 2048; Kd = 512; }
  else if (role == 2) { wsrc = imgWih1 + (size_t)g * 8192; npkt = 8192; Kd = 2048; }
  else                { wsrc = imgWhh1 + (size_t)g * 8192; npkt = 8192; Kd = 2048; }
  for (int i = tid; i < npkt; i += 512) smem[i] = wsrc[i];
  __syncthreads();
  const bf16x8* wlds = reinterpret_cast<const bf16x8*>(smem);
  const int row0 = wh * 32 + l15;
  const int nb = Kd >> 9;            // batches (8 ktiles ea) per K-half
  const int khe = half * (Kd >> 1);  // element base of my K-half
  const int kt0 = khe >> 5;

  for (int t = 0; t < Tn; ++t) {
    // ---- waits ----
    if (role == 0) {
      const bool ring = (t + 1 > R0);
      for (;;) {
        int ok = 1;
        if (tid < 64) ok = (ldf(&fA0r[tid]) >= (uint32_t)t);
        else if (tid == 64) ok = (ldf(flags + FXS + g * 16) >= (uint32_t)(t + 1));
        else if (ring && tid >= 128 && tid < 192) ok = (ldf(&fB0r[tid - 128]) >= (uint32_t)(t + 1 - R0));
        if (__syncthreads_and(ok)) break;
        __builtin_amdgcn_s_sleep(1);
      }
    } else if (role == 1) {
      if (t >= 2) {
        for (;;) {
          int ok = 1;
          if (tid == 0) ok = (ldf(&fA0r[g]) >= (uint32_t)(t - 1));
          if (__syncthreads_and(ok)) break;
          __builtin_amdgcn_s_sleep(2);
        }
      }
    } else if (role == 2) {
      const bool ring = (t + 2 > R1);
      for (;;) {
        int ok = 1;
        if (tid < 64) ok = (ldf(&fA0r[tid]) >= (uint32_t)(t + 1));
        else if (tid == 64) ok = (ldf(&fP1r[g]) >= (uint32_t)(t + 1));
        else if (ring && tid >= 128 && tid < 192) ok = (ldf(&fP1r[tid - 128]) >= (uint32_t)(t + 2 - R1));
        if (__syncthreads_and(ok)) break;
        __builtin_amdgcn_s_sleep(1);
      }
    } else {
      for (;;) {
        int ok = 1;
        if (tid < 64) ok = (ldf(&fB0r[tid]) >= (uint32_t)t);
        if (__syncthreads_and(ok)) break;
        __builtin_amdgcn_s_sleep(1);
      }
    }
    __builtin_amdgcn_fence(__ATOMIC_ACQUIRE, "workgroup");

    // ---- A source ----
    const unsigned short* asrc; int astride;
    if (role == 0)      { asrc = h0ring + (size_t)((t + R0 - 1) % R0) * HSLOT; astride = Hn; }
    else if (role == 1) { asrc = xall + (size_t)t * (Bn * En); astride = En; }
    else if (role == 2) { asrc = h0ring + (size_t)(t % R0) * HSLOT; astride = Hn; }
    else                { asrc = h1ring + (size_t)((t + R1 - 1) % R1) * HSLOT; astride = Hn; }

    f32x4 acc[2][2];
#pragma unroll
    for (int mt = 0; mt < 2; ++mt)
#pragma unroll
      for (int ct = 0; ct < 2; ++ct) acc[mt][ct] = (f32x4){0.f, 0.f, 0.f, 0.f};

    const unsigned short* pr0 = asrc + (size_t)row0 * astride + khe + kq * 8;
    const unsigned short* pr1 = pr0 + (size_t)16 * astride;
    for (int b = 0; b < nb; ++b) {
      const unsigned short* pa = pr0 + b * 256;
      const unsigned short* pb = pr1 + b * 256;
      bf16x8 v0, v1, v2, v3, v4, v5, v6, v7, v8, v9, va, vb, vc, vd, ve, vf;
      asm volatile(
          "global_load_dwordx4 %[t0], %[a], off sc0 sc1\n\t"
          "global_load_dwordx4 %[t1], %[a], off offset:64 sc0 sc1\n\t"
          "global_load_dwordx4 %[t2], %[a], off offset:128 sc0 sc1\n\t"
          "global_load_dwordx4 %[t3], %[a], off offset:192 sc0 sc1\n\t"
          "global_load_dwordx4 %[t4], %[a], off offset:256 sc0 sc1\n\t"
          "global_load_dwordx4 %[t5], %[a], off offset:320 sc0 sc1\n\t"
          "global_load_dwordx4 %[t6], %[a], off offset:384 sc0 sc1\n\t"
          "global_load_dwordx4 %[t7], %[a], off offset:448 sc0 sc1\n\t"
          "global_load_dwordx4 %[t8], %[b], off sc0 sc1\n\t"
          "global_load_dwordx4 %[t9], %[b], off offset:64 sc0 sc1\n\t"
          "global_load_dwordx4 %[ta], %[b], off offset:128 sc0 sc1\n\t"
          "global_load_dwordx4 %[tb], %[b], off offset:192 sc0 sc1\n\t"
          "global_load_dwordx4 %[tc], %[b], off offset:256 sc0 sc1\n\t"
          "global_load_dwordx4 %[td], %[b], off offset:320 sc0 sc1\n\t"
          "global_load_dwordx4 %[te], %[b], off offset:384 sc0 sc1\n\t"
          "global_load_dwordx4 %[tf], %[b], off offset:448 sc0 sc1\n\t"
          "s_waitcnt vmcnt(0)"
          : [t0]"=&v"(v0), [t1]"=&v"(v1), [t2]"=&v"(v2), [t3]"=&v"(v3),
            [t4]"=&v"(v4), [t5]"=&v"(v5), [t6]"=&v"(v6), [t7]"=&v"(v7),
            [t8]"=&v"(v8), [t9]"=&v"(v9), [ta]"=&v"(va), [tb]"=&v"(vb),
            [tc]"=&v"(vc), [td]"=&v"(vd), [te]"=&v"(ve), [tf]"=&v"(vf)
          : [a]"v"(pa), [b]"v"(pb)
          : "memory");
      __builtin_amdgcn_sched_barrier(0);
      const int ktg = kt0 + b * 8;
#define MFMA4(AF0, AF1, KT) do { \
        bf16x8 bw0 = wlds[((KT) * 2) * 64 + l]; \
        bf16x8 bw1 = wlds[((KT) * 2 + 1) * 64 + l]; \
        acc[0][0] = __builtin_amdgcn_mfma_f32_16x16x32_bf16(AF0, bw0, acc[0][0], 0, 0, 0); \
        acc[0][1] = __builtin_amdgcn_mfma_f32_16x16x32_bf16(AF0, bw1, acc[0][1], 0, 0, 0); \
        acc[1][0] = __builtin_amdgcn_mfma_f32_16x16x32_bf16(AF1, bw0, acc[1][0], 0, 0, 0); \
        acc[1][1] = __builtin_amdgcn_mfma_f32_16x16x32_bf16(AF1, bw1, acc[1][1], 0, 0, 0); \
      } while (0)
      MFMA4(v0, v8, ktg + 0); MFMA4(v1, v9, ktg + 1);
      MFMA4(v2, va, ktg + 2); MFMA4(v3, vb, ktg + 3);
      MFMA4(v4, vc, ktg + 4); MFMA4(v5, vd, ktg + 5);
      MFMA4(v6, ve, ktg + 6); MFMA4(v7, vf, ktg + 7);
#undef MFMA4
    }

    // ---- cross-half accumulator reduce via LDS ----
    __syncthreads();
    if (half == 1) {
#pragma unroll
      for (int mt = 0; mt < 2; ++mt)
#pragma unroll
        for (int ct = 0; ct < 2; ++ct)
          rbuf[(wh * 4 + mt * 2 + ct) * 64 + l] = acc[mt][ct];
    }
    __syncthreads();

    // ---- epilogues (half 0 holds the full sum) ----
    if (half == 0) {
#pragma unroll
      for (int mt = 0; mt < 2; ++mt)
#pragma unroll
        for (int ct = 0; ct < 2; ++ct)
          acc[mt][ct] += rbuf[(wh * 4 + mt * 2 + ct) * 64 + l];

      if (role == 0 || role == 2) {
        const float* pb2 = (role == 0 ? xpbuf : bpbuf) + (size_t)(g * 2 + (t & 1)) * 4096;
        const float* bsrc = (role == 0) ? bias0 : bias1;
        unsigned short* hdst = (role == 0) ? (h0ring + (size_t)(t % R0) * HSLOT)
                                           : (h1ring + (size_t)(t % R1) * HSLOT);
#pragma unroll
        for (int mt = 0; mt < 2; ++mt) {
#pragma unroll
          for (int ct = 0; ct < 2; ++ct) {
            const int idx = (wh * 4 + mt * 2 + ct) * 256 + l * 4;
            f32x4 sum = acc[mt][ct] + ld_p(pb2 + idx);
            const int col = g * 32 + ct * 16 + l15;
            const float bb = bsrc[col];
#pragma unroll
            for (int r = 0; r < 4; ++r) {
              float v = tanhf(sum[r] + bb);
              int bo = f2b(v);
              int po = __shfl_down(bo, 1);
              if ((l15 & 1) == 0) {
                const int row = wh * 32 + mt * 16 + kq * 4 + r;
                uint32_t packed = (uint32_t)(unsigned short)bo | ((uint32_t)(unsigned short)po << 16);
                stf((uint32_t*)(hdst + (size_t)row * Hn + col), packed);
              }
            }
          }
        }
      } else {
        float* dst = (role == 1 ? xpbuf : bpbuf) + (size_t)(g * 2 + (t & 1)) * 4096;
#pragma unroll
        for (int mt = 0; mt < 2; ++mt)
#pragma unroll
          for (int ct = 0; ct < 2; ++ct)
            st_p(dst + (wh * 4 + mt * 2 + ct) * 256 + l * 4, acc[mt][ct]);
      }
    }
    drain_then_sync();
    if (role == 0)      { if (tid < NREP) stf(flags + (size_t)tid * 1024 + g, (uint32_t)(t + 1)); }
    else if (role == 1) { if (tid == 0) stf(flags + FXS + g * 16, (uint32_t)(t + 1)); }
    else if (role == 2) { if (tid < NREP) stf(flags + (size_t)tid * 1024 + 128 + g, (uint32_t)(t + 1)); }
    else                { if (tid < NREP) stf(flags + (size_t)tid * 1024 + 256 + g, (uint32_t)(t + 1)); }
  }
}

// ---------------- head (unchanged from r4, proven) ----------------
__global__ __launch_bounds__(256) void head1(const uint4* __restrict__ imgW1,
                                             const unsigned short* __restrict__ h1f,
                                             const float* __restrict__ b1,
                                             unsigned short* __restrict__ a1) {
  __shared__ uint4 smem[4096];
  const int tid = threadIdx.x;
  const int w = tid >> 6, l = tid & 63, l15 = l & 15, kq = l >> 4;
  const int g = blockIdx.x;
  const uint4* src = imgW1 + (size_t)g * 4096;
  for (int i = tid; i < 4096; i += 256) smem[i] = src[i];
  __syncthreads();
  const bf16x8* wlds = reinterpret_cast<const bf16x8*>(smem);
  const int row0 = w * 32 + l15;
  f32x4 acc[2];
  acc[0] = (f32x4){0.f, 0.f, 0.f, 0.f};
  acc[1] = (f32x4){0.f, 0.f, 0.f, 0.f};
#pragma unroll 4
  for (int kt = 0; kt < 64; ++kt) {
    bf16x8 af0 = *reinterpret_cast<const bf16x8*>(h1f + (size_t)row0 * Hn + kt * 32 + kq * 8);
    bf16x8 af1 = *reinterpret_cast<const bf16x8*>(h1f + (size_t)(row0 + 16) * Hn + kt * 32 + kq * 8);
    bf16x8 bf = wlds[kt * 64 + l];
    acc[0] = __builtin_amdgcn_mfma_f32_16x16x32_bf16(af0, bf, acc[0], 0, 0, 0);
    acc[1] = __builtin_amdgcn_mfma_f32_16x16x32_bf16(af1, bf, acc[1], 0, 0, 0);
  }
  const int col = g * 16 + l15;
  const float bb = b1[col];
#pragma unroll
  for (int mt = 0; mt < 2; ++mt)
#pragma unroll
    for (int r = 0; r < 4; ++r) {
      float v = fmaxf(acc[mt][r] + bb, 0.f);
      const int row = w * 32 + mt * 16 + kq * 4 + r;
      a1[(size_t)row * En + col] = f2b(v);
    }
}

__global__ __launch_bounds__(256) void head2(const uint4* __restrict__ imgW2,
                                             const unsigned short* __restrict__ a1,
                                             const float* __restrict__ b2,
                                             float* __restrict__ out) {
  __shared__ uint4 smem[4096];
  const int tid = threadIdx.x;
  const int w = tid >> 6, l = tid & 63, l15 = l & 15, kq = l >> 4;
  const int g = blockIdx.x;
  const uint4* src = imgW2 + (size_t)g * 4096;
  for (int i = tid; i < 4096; i += 256) smem[i] = src[i];
  __syncthreads();
  const bf16x8* wlds = reinterpret_cast<const bf16x8*>(smem);
  const int row0 = w * 32 + l15;
  f32x4 acc[2][4];
#pragma unroll
  for (int mt = 0; mt < 2; ++mt)
#pragma unroll
    for (int ct = 0; ct < 4; ++ct) acc[mt][ct] = (f32x4){0.f, 0.f, 0.f, 0.f};
#pragma unroll
  for (int kt = 0; kt < 16; ++kt) {
    bf16x8 af0 = *reinterpret_cast<const bf16x8*>(a1 + (size_t)row0 * En + kt * 32 + kq * 8);
    bf16x8 af1 = *reinterpret_cast<const bf16x8*>(a1 + (size_t)(row0 + 16) * En + kt * 32 + kq * 8);
#pragma unroll
    for (int ct = 0; ct < 4; ++ct) {
      bf16x8 bf = wlds[(kt * 4 + ct) * 64 + l];
      acc[0][ct] = __builtin_amdgcn_mfma_f32_16x16x32_bf16(af0, bf, acc[0][ct], 0, 0, 0);
      acc[1][ct] = __builtin_amdgcn_mfma_f32_16x16x32_bf16(af1, bf, acc[1][ct], 0, 0, 0);
    }
  }
#pragma unroll
  for (int mt = 0; mt < 2; ++mt)
#pragma unroll
    for (int ct = 0; ct < 4; ++ct) {
      const int col = g * 64 + ct * 16 + l15;
      const float bb = b2[col];
#pragma unroll
      for (int r = 0; r < 4; ++r) {
        const int row = w * 32 + mt * 16 + kq * 4 + r;
        out[(size_t)row * Vn + col] = acc[mt][ct][r] + bb;
      }
    }
}

// ---------------- launch ----------------
extern "C" void kernel_launch(void* const* d_in, const int* in_sizes, int n_in,
                              void* d_out, int out_size, void* d_ws, size_t ws_size,
                              hipStream_t stream) {
  (void)in_sizes; (void)n_in; (void)out_size;
  const int* ids    = (const int*)d_in[0];
  const float* emb  = (const float*)d_in[1];
  const float* Wih0 = (const float*)d_in[2];
  const float* Whh0 = (const float*)d_in[3];
  const float* bih0 = (const float*)d_in[4];
  const float* bhh0 = (const float*)d_in[5];
  const float* Wih1 = (const float*)d_in[6];
  const float* Whh1 = (const float*)d_in[7];
  const float* bih1 = (const float*)d_in[8];
  const float* bhh1 = (const float*)d_in[9];
  const float* W1   = (const float*)d_in[10];
  const float* b1   = (const float*)d_in[11];
  const float* W2   = (const float*)d_in[12];
  const float* b2   = (const float*)d_in[13];
  float* out = (float*)d_out;

  char* ws = (char*)d_ws;
  size_t o = 0;
  auto alloc = [&](size_t bytes) -> char* {
    char* p = ws + o;
    o += (bytes + 255) & ~(size_t)255;
    return p;
  };
  uint32_t* flags = (uint32_t*)alloc(FLAG_WORDS * 4);
  float* bias0 = (float*)alloc(Hn * 4);
  float* bias1 = (float*)alloc(Hn * 4);
  unsigned short* h0ring = (unsigned short*)alloc((size_t)R0 * HSLOT * 2);
  unsigned short* h1ring = (unsigned short*)alloc((size_t)R1 * HSLOT * 2);
  float* xpbuf = (float*)alloc(64ull * 2 * 4096 * 4);
  float* bpbuf = (float*)alloc(64ull * 2 * 4096 * 4);
  unsigned short* a1 = (unsigned short*)alloc((size_t)Bn * En * 2);
  uint4* imgWhh0 = (uint4*)alloc(64ull * 8192 * 16);
  uint4* imgWih0 = (uint4*)alloc(64ull * 2048 * 16);
  uint4* imgWih1 = (uint4*)alloc(64ull * 8192 * 16);
  uint4* imgWhh1 = (uint4*)alloc(64ull * 8192 * 16);
  uint4* imgW1 = (uint4*)alloc(32ull * 4096 * 16);
  uint4* imgW2 = (uint4*)alloc(500ull * 4096 * 16);
  uint4* xall  = (uint4*)alloc((size_t)Tn * Bn * En * 2);
  if (o > ws_size) return;  // fail visibly, no OOB

  zero3<<<512, 256, 0, stream>>>(flags, FLAG_WORDS,
                                 (uint32_t*)(h0ring + (size_t)(R0 - 1) * HSLOT), 131072,
                                 (uint32_t*)(h1ring + (size_t)(R1 - 1) * HSLOT), 131072);
  pack_bias<<<8, 256, 0, stream>>>(bih0, bhh0, bih1, bhh1, bias0, bias1);
  pack_w32<<<2048, 256, 0, stream>>>(Whh0, 2048, imgWhh0);
  pack_w32<<<512, 256, 0, stream>>>(Wih0, 512, imgWih0);
  pack_w32<<<2048, 256, 0, stream>>>(Wih1, 2048, imgWih1);
  pack_w32<<<2048, 256, 0, stream>>>(Whh1, 2048, imgWhh1);
  pack_imgW1<<<512, 256, 0, stream>>>(W1, imgW1);
  pack_imgW2<<<8000, 256, 0, stream>>>(W2, imgW2);
  gather_x<<<16384, 256, 0, stream>>>(ids, emb, xall);

  rnn_persist<<<256, 512, 0, stream>>>(imgWhh0, imgWih0, imgWih1, imgWhh1,
                                       (const unsigned short*)xall, h0ring, h1ring,
                                       xpbuf, bpbuf, bias0, bias1, flags);

  head1<<<32, 256, 0, stream>>>(imgW1, h1ring + (size_t)(511 % R1) * HSLOT, b1, a1);
  head2<<<500, 256, 0, stream>>>(imgW2, a1, b2, out);
}